// Round 5
// baseline (1679.238 us; speedup 1.0000x reference)
//
#include <hip/hip_runtime.h>
#include <math.h>

#define TT 4
#define CC 3
#define HH 192
#define WW 192
#define SS 300
#define SP 320              // padded superpixel count (pad masked -inf)
#define HW (HH*WW)
#define NPL 38              // stored E planes per frame (38*8 = 304 >= 300)
#define SIMS_OFF 16384      // float index of E table in ws
#define ZPB (152*HW*16)     // byte offset of zero pad from table base (152 = TT*NPL)
#define IZ_OFF (SIMS_OFF + ZPB/4 + 256)   // float index of iZ planes [t][HW]

typedef _Float16 h8 __attribute__((ext_vector_type(8)));
typedef _Float16 h2 __attribute__((ext_vector_type(2)));

// ---------- ws layout (floats) ----------
// [0, 3600)       sums [T][S][3]
// [3600, 4800)    cnts [T][S]
// [4800, 9920)    means float4 [T][SP]: (20mx, 20my, 20mz, -10|m|^2 | -inf absent)
// [SIMS_OFF ...)  E table fp16: [t*38+s8][HW][8 halves], then 1KB zero pad, then iZ [T][HW] f32

__global__ void k_zero(float* ws) {
    int i = blockIdx.x * 256 + threadIdx.x;
    if (i < TT * SS * 4) { ws[i] = 0.f; return; }
    int j = i - TT * SS * 4;
    if (j < 256) ws[SIMS_OFF + ZPB / 4 + j] = 0.f;   // zero pad (OOB / tail staging source)
}

__global__ void k_accum(const float* __restrict__ x, const int* __restrict__ spix,
                        float* __restrict__ ws) {
    int i = blockIdx.x * 256 + threadIdx.x;
    if (i >= TT * HW) return;
    int t = i / HW, p = i - t * HW;
    int s = spix[i];
    float* sums = ws;
    float* cnts = ws + TT * SS * 3;
    int b = (t * SS + s) * 3;
    atomicAdd(&sums[b + 0], x[(t * 3 + 0) * HW + p]);
    atomicAdd(&sums[b + 1], x[(t * 3 + 1) * HW + p]);
    atomicAdd(&sums[b + 2], x[(t * 3 + 2) * HW + p]);
    atomicAdd(&cnts[t * SS + s], 1.f);
}

__global__ void k_means(float* __restrict__ ws) {
    int i = blockIdx.x * 256 + threadIdx.x;
    if (i >= TT * SP) return;
    int t = i / SP, s = i - t * SP;
    const float* sums = ws;
    const float* cnts = ws + TT * SS * 3;
    float4* m4 = (float4*)(ws + 4800);
    float4 m;
    if (s < SS) {
        float c = cnts[t * SS + s];
        float inv = 1.f / fmaxf(c, 1.f);
        float mx = sums[(t * SS + s) * 3 + 0] * inv;
        float my = sums[(t * SS + s) * 3 + 1] * inv;
        float mz = sums[(t * SS + s) * 3 + 2] * inv;
        m.x = 20.f * mx; m.y = 20.f * my; m.z = 20.f * mz;
        m.w = (c > 0.f) ? (-10.f * (mx * mx + my * my + mz * mz)) : -INFINITY;
    } else {
        m.x = 0.f; m.y = 0.f; m.z = 0.f; m.w = -INFINITY;
    }
    m4[t * SP + s] = m;
}

// ---- per-pixel max-shifted unnormalized E (fp16) + iZ, 2 passes over SP ----
__launch_bounds__(256)
__global__ void k_sims(const float* __restrict__ x, float* __restrict__ ws) {
    __shared__ float4 sm[SP];
    const int tid = threadIdx.x;
    const int t = blockIdx.y;
    const int p = blockIdx.x * 256 + tid;
    const float4* m4 = (const float4*)(ws + 4800) + t * SP;
    for (int i = tid; i < SP; i += 256) sm[i] = m4[i];
    __syncthreads();
    const float fx = x[(t * 3 + 0) * HW + p];
    const float fy = x[(t * 3 + 1) * HW + p];
    const float fz = x[(t * 3 + 2) * HW + p];

    float M0 = -INFINITY, M1 = -INFINITY, M2 = -INFINITY, M3 = -INFINITY;
#pragma unroll 4
    for (int s = 0; s < SP; s += 4) {
        float4 ma = sm[s], mb = sm[s + 1], mc = sm[s + 2], md = sm[s + 3];
        M0 = fmaxf(M0, fmaf(fx, ma.x, fmaf(fy, ma.y, fmaf(fz, ma.z, ma.w))));
        M1 = fmaxf(M1, fmaf(fx, mb.x, fmaf(fy, mb.y, fmaf(fz, mb.z, mb.w))));
        M2 = fmaxf(M2, fmaf(fx, mc.x, fmaf(fy, mc.y, fmaf(fz, mc.z, mc.w))));
        M3 = fmaxf(M3, fmaf(fx, md.x, fmaf(fy, md.y, fmaf(fz, md.z, md.w))));
    }
    const float M = fmaxf(fmaxf(M0, M1), fmaxf(M2, M3));

    float Z0 = 0.f, Z1 = 0.f;
    char* tbb = (char*)(ws + SIMS_OFF);
#pragma unroll 2
    for (int s8 = 0; s8 < NPL; s8++) {
        h8 v;
#pragma unroll
        for (int j = 0; j < 8; j++) {
            float4 m = sm[s8 * 8 + j];
            float e = __expf(fmaf(fx, m.x, fmaf(fy, m.y, fmaf(fz, m.z, m.w))) - M);
            if (j & 1) Z1 += e; else Z0 += e;
            v[j] = (_Float16)e;
        }
        *(h8*)(tbb + ((long)(t * NPL + s8) * HW + p) * 16) = v;
    }
    ws[IZ_OFF + t * HW + p] = 1.f / (Z0 + Z1);
}

// ================= fused attn + norm + linear =================
// tile 32x16, 256 threads, 2 adjacent px/thread. Halo 22 rows x 38 cols.
// LDS ssim: slot g holds E-block for b = g ^ (hy&1) (bank-spread involution),
// staged via global_load_lds with pre-swizzled SOURCE addresses (LDS linear).

__device__ __forceinline__ float dot8(h8 a, h8 b, float c) {
    c = __builtin_amdgcn_fdot2(__builtin_shufflevector(a, a, 0, 1), __builtin_shufflevector(b, b, 0, 1), c, false);
    c = __builtin_amdgcn_fdot2(__builtin_shufflevector(a, a, 2, 3), __builtin_shufflevector(b, b, 2, 3), c, false);
    c = __builtin_amdgcn_fdot2(__builtin_shufflevector(a, a, 4, 5), __builtin_shufflevector(b, b, 4, 5), c, false);
    c = __builtin_amdgcn_fdot2(__builtin_shufflevector(a, a, 6, 7), __builtin_shufflevector(b, b, 6, 7), c, false);
    return c;
}

// one window entry (dy'=D 0..6, dx'=X 0..7): 4 plane reads, dot into
// a0[7D+X] (px0, valid X<7) and a1[7D+X-1] (px1, valid X>0)
template<int D, int X>
__device__ __forceinline__ void entry(const char* ss, int bE0, int bE1, int bO0, int bO1,
                                      const h8* o0, const h8* o1, float* a0, float* a1) {
    const int base = (X & 1) ? ((D & 1) ? bO1 : bO0) : ((D & 1) ? bE1 : bE0);
    float sA0 = 0.f, sB0 = 0.f, sA1 = 0.f, sB1 = 0.f;
#pragma unroll
    for (int jd = 0; jd < 4; jd++) {
        h8 q = *(const h8*)(ss + base + (jd * 836 + D * 38 + X) * 16);
        if (X < 7) { if (jd & 1) sB0 = dot8(o0[jd], q, sB0); else sA0 = dot8(o0[jd], q, sA0); }
        if (X > 0) { if (jd & 1) sB1 = dot8(o1[jd], q, sB1); else sA1 = dot8(o1[jd], q, sA1); }
    }
    if (X < 7) a0[7 * D + X] += sA0 + sB0;
    if (X > 0) a1[7 * D + X - 1] += sA1 + sB1;
}

#define ECALL(D, X) entry<D, X>(ssc, bE0, bE1, bO0, bO1, o0, o1, a0, a1);
#define EROW(D) ECALL(D,0) ECALL(D,1) ECALL(D,2) ECALL(D,3) ECALL(D,4) ECALL(D,5) ECALL(D,6) ECALL(D,7)

__launch_bounds__(256, 2)
__global__ void k_main(const float* __restrict__ x, const float* __restrict__ Wlin,
                       const float* __restrict__ blin, const float* __restrict__ ws,
                       float* __restrict__ out) {
    __shared__ __align__(16) _Float16 ssim[3584 * 8];   // 57344 B
    __shared__ float4 sfh[22 * 39];                     // features + iZ (stride 39: bank spread)
    __shared__ float  sW[441];

    const int tid = threadIdx.x;
    const int tx = tid & 15, ty = tid >> 4, lane = tid & 63;
    const int t = blockIdx.z;
    const int gx0 = blockIdx.x * 32 - 3, gy0 = blockIdx.y * 16 - 3;
    const int tx2 = tx * 2;
    const char* tb = (const char*)(ws + SIMS_OFF);
    const char* ssc = (const char*)ssim;

    // staging descriptors: slot g = j*256+tid holds block b = g ^ (hy&1)
    int off[14], step[14], mask9 = 0;
    const int zp_off = ZPB + lane * 16;
#pragma unroll
    for (int j = 0; j < 14; j++) {
        int g = j * 256 + tid;
        int jd = g / 836;                   // 0..4 (tail slots -> pad)
        int r = g - jd * 836;
        int hy = r / 38, hx0 = r - hy * 38;
        int hxs = hx0 ^ (hy & 1);           // source-side involution
        int gy = gy0 + hy, gx = gx0 + hxs;
        bool ok = (jd < 4) & (gy >= 0) & (gy < HH) & (gx >= 0) & (gx < WW);
        off[j] = ok ? ((t * NPL + jd) * HW + gy * WW + gx) * 16 : zp_off;
        step[j] = ok ? 4 * HW * 16 : 0;
        if (jd >= 2) mask9 |= (1 << j);     // chunk 9 planes 38/39 don't exist -> pad
    }

#define STAGE(cc) { _Pragma("unroll") \
    for (int j = 0; j < 14; j++) { \
        int o = (((cc) == 9) && ((mask9 >> j) & 1)) ? zp_off : off[j]; \
        __builtin_amdgcn_global_load_lds((const void*)(tb + o), \
            (void*)((char*)ssim + (j * 256 + (tid & 192)) * 16), 16, 0, 0); \
        off[j] += step[j]; } }

    STAGE(0)

    for (int i = tid; i < 441; i += 256) sW[i] = Wlin[i];
    const float* izp = ws + IZ_OFF + t * HW;
    for (int hp = tid; hp < 836; hp += 256) {
        int hy = hp / 38, hx = hp - hy * 38;
        int gy = gy0 + hy, gx = gx0 + hx;
        bool inb = (gy >= 0 && gy < HH && gx >= 0 && gx < WW);
        float4 f = make_float4(0.f, 0.f, 0.f, 0.f);
        if (inb) {
            int p = gy * WW + gx;
            f.x = x[(t * 3 + 0) * HW + p];
            f.y = x[(t * 3 + 1) * HW + p];
            f.z = x[(t * 3 + 2) * HW + p];
            f.w = izp[p];
        }
        sfh[hy * 39 + hx] = f;
    }
    __syncthreads();

    // LDS read bases: addr = (b ^ rp)*16 = base(parity(X), parity(D)) + imm
    const int B0 = (ty * 38 + tx2) * 16;
    const int tp = (ty & 1) * 16;
    const int bE0 = B0 + tp,        bO0 = B0 - tp;         // D even: X even / X odd
    const int bE1 = B0 + (16 - tp), bO1 = B0 - (16 - tp);  // D odd

    float a0[49], a1[49];
#pragma unroll
    for (int k = 0; k < 49; k++) { a0[k] = 0.f; a1[k] = 0.f; }

#pragma unroll 1
    for (int c = 0; c < 10; ++c) {
        h8 o0[4], o1[4];
#pragma unroll
        for (int jd = 0; jd < 4; jd++) {                    // own px: (D=3,X=3) and (D=3,X=4)
            o0[jd] = *(const h8*)(ssc + bO1 + (jd * 836 + 3 * 38 + 3) * 16);
            o1[jd] = *(const h8*)(ssc + bE1 + (jd * 836 + 3 * 38 + 4) * 16);
        }
        EROW(0) EROW(1) EROW(2) EROW(3) EROW(4) EROW(5) EROW(6)
        __syncthreads();
        if (c < 9) { STAGE(c + 1) }
        __syncthreads();
    }

    // ---- normalize (eps+max semantics) + linear epilogue ----
    float mx0 = 0.f, mx1 = 0.f;
#pragma unroll
    for (int k = 0; k < 49; k++) {
        int qi = (ty + k / 7) * 39 + tx2 + k % 7;
        a0[k] *= sfh[qi].w;                 // * iZ_q
        a1[k] *= sfh[qi + 1].w;
        mx0 = fmaxf(mx0, a0[k]);
        mx1 = fmaxf(mx1, a1[k]);
    }
    const float iZ0 = sfh[(ty + 3) * 39 + tx2 + 3].w;
    const float iZ1 = sfh[(ty + 3) * 39 + tx2 + 4].w;
    const float inv0 = 1.f / (1e-5f / iZ0 + mx0);
    const float inv1 = 1.f / (1e-5f / iZ1 + mx1);

    float o00 = blin[0], o01 = blin[1], o02 = blin[2];
    float o10 = blin[0], o11 = blin[1], o12 = blin[2];
#pragma unroll
    for (int k = 0; k < 49; k++) {
        int qi = (ty + k / 7) * 39 + tx2 + k % 7;
        float4 f0 = sfh[qi];
        float4 f1 = sfh[qi + 1];
        float r0 = a0[k] * inv0, r1 = a1[k] * inv1;
        o00 += r0 * (sW[k] * f0.x + sW[49 + k] * f0.y + sW[98 + k] * f0.z);
        o01 += r0 * (sW[147 + k] * f0.x + sW[196 + k] * f0.y + sW[245 + k] * f0.z);
        o02 += r0 * (sW[294 + k] * f0.x + sW[343 + k] * f0.y + sW[392 + k] * f0.z);
        o10 += r1 * (sW[k] * f1.x + sW[49 + k] * f1.y + sW[98 + k] * f1.z);
        o11 += r1 * (sW[147 + k] * f1.x + sW[196 + k] * f1.y + sW[245 + k] * f1.z);
        o12 += r1 * (sW[294 + k] * f1.x + sW[343 + k] * f1.y + sW[392 + k] * f1.z);
    }
    int p = (gy0 + 3 + ty) * WW + gx0 + 3 + tx2;
    *(float2*)&out[(t * 3 + 0) * HW + p] = make_float2(o00, o10);
    *(float2*)&out[(t * 3 + 1) * HW + p] = make_float2(o01, o11);
    *(float2*)&out[(t * 3 + 2) * HW + p] = make_float2(o02, o12);
}

extern "C" void kernel_launch(void* const* d_in, const int* in_sizes, int n_in,
                              void* d_out, int out_size, void* d_ws, size_t ws_size,
                              hipStream_t stream) {
    (void)in_sizes; (void)n_in; (void)out_size; (void)ws_size;
    const float* x    = (const float*)d_in[0];
    const int*   spix = (const int*)d_in[1];
    const float* Wlin = (const float*)d_in[2];
    const float* blin = (const float*)d_in[3];
    float* out = (float*)d_out;
    float* ws  = (float*)d_ws;

    hipLaunchKernelGGL(k_zero,  dim3(20), dim3(256), 0, stream, ws);
    hipLaunchKernelGGL(k_accum, dim3((TT * HW + 255) / 256), dim3(256), 0, stream, x, spix, ws);
    hipLaunchKernelGGL(k_means, dim3((TT * SP + 255) / 256), dim3(256), 0, stream, ws);
    hipLaunchKernelGGL(k_sims,  dim3(HW / 256, TT), dim3(256), 0, stream, x, ws);
    hipLaunchKernelGGL(k_main,  dim3(WW / 32, HH / 16, TT), dim3(256), 0, stream,
                       x, Wlin, blin, ws, out);
}

// Round 6
// 195.558 us; speedup vs baseline: 8.5869x; 8.5869x over previous
//
#include <hip/hip_runtime.h>
#include <math.h>

#define TT 4
#define CC 3
#define HH 192
#define WW 192
#define SS 300
#define SP 320              // padded superpixel count (pad masked -inf)
#define HW (HH*WW)
#define NPL 38              // stored E planes per frame (38*8 = 304 >= 300)
#define SIMS_OFF 16384      // float index of E table in ws
#define ZPB (152*HW*16)     // byte offset of zero pad from table base (152 = TT*NPL)
#define IZ_OFF (SIMS_OFF + ZPB/4 + 256)   // float index of iZ planes [t][HW]
#define PD 3
#define HSZ 22
#define NHP (HSZ*HSZ)       // 484
#define NSLOT (4*NHP)       // 1936 slots (16B each) per chunk

typedef _Float16 h8 __attribute__((ext_vector_type(8)));

// ---------- ws layout (floats) ----------
// [0, 3600)       sums [T][S][3]
// [3600, 4800)    cnts [T][S]
// [4800, 9920)    means float4 [T][SP]: (20mx, 20my, 20mz, -10|m|^2 | -inf absent)
// [SIMS_OFF ...)  E table fp16: [t*38+s8][HW][8 halves], then 1KB zero pad, then iZ [T][HW] f32

__global__ void k_zero(float* ws) {
    int i = blockIdx.x * 256 + threadIdx.x;
    if (i < TT * SS * 4) { ws[i] = 0.f; return; }
    int j = i - TT * SS * 4;
    if (j < 256) ws[SIMS_OFF + ZPB / 4 + j] = 0.f;   // zero pad (OOB / tail staging source)
}

__global__ void k_accum(const float* __restrict__ x, const int* __restrict__ spix,
                        float* __restrict__ ws) {
    int i = blockIdx.x * 256 + threadIdx.x;
    if (i >= TT * HW) return;
    int t = i / HW, p = i - t * HW;
    int s = spix[i];
    float* sums = ws;
    float* cnts = ws + TT * SS * 3;
    int b = (t * SS + s) * 3;
    atomicAdd(&sums[b + 0], x[(t * 3 + 0) * HW + p]);
    atomicAdd(&sums[b + 1], x[(t * 3 + 1) * HW + p]);
    atomicAdd(&sums[b + 2], x[(t * 3 + 2) * HW + p]);
    atomicAdd(&cnts[t * SS + s], 1.f);
}

__global__ void k_means(float* __restrict__ ws) {
    int i = blockIdx.x * 256 + threadIdx.x;
    if (i >= TT * SP) return;
    int t = i / SP, s = i - t * SP;
    const float* sums = ws;
    const float* cnts = ws + TT * SS * 3;
    float4* m4 = (float4*)(ws + 4800);
    float4 m;
    if (s < SS) {
        float c = cnts[t * SS + s];
        float inv = 1.f / fmaxf(c, 1.f);
        float mx = sums[(t * SS + s) * 3 + 0] * inv;
        float my = sums[(t * SS + s) * 3 + 1] * inv;
        float mz = sums[(t * SS + s) * 3 + 2] * inv;
        m.x = 20.f * mx; m.y = 20.f * my; m.z = 20.f * mz;
        m.w = (c > 0.f) ? (-10.f * (mx * mx + my * my + mz * mz)) : -INFINITY;
    } else {
        m.x = 0.f; m.y = 0.f; m.z = 0.f; m.w = -INFINITY;
    }
    m4[t * SP + s] = m;
}

// ---- per-pixel max-shifted unnormalized E (fp16) + iZ ----
__launch_bounds__(256)
__global__ void k_sims(const float* __restrict__ x, float* __restrict__ ws) {
    __shared__ float4 sm[SP];
    const int tid = threadIdx.x;
    const int t = blockIdx.y;
    const int p = blockIdx.x * 256 + tid;
    const float4* m4 = (const float4*)(ws + 4800) + t * SP;
    for (int i = tid; i < SP; i += 256) sm[i] = m4[i];
    __syncthreads();
    const float fx = x[(t * 3 + 0) * HW + p];
    const float fy = x[(t * 3 + 1) * HW + p];
    const float fz = x[(t * 3 + 2) * HW + p];

    float M0 = -INFINITY, M1 = -INFINITY, M2 = -INFINITY, M3 = -INFINITY;
#pragma unroll 4
    for (int s = 0; s < SP; s += 4) {
        float4 ma = sm[s], mb = sm[s + 1], mc = sm[s + 2], md = sm[s + 3];
        M0 = fmaxf(M0, fmaf(fx, ma.x, fmaf(fy, ma.y, fmaf(fz, ma.z, ma.w))));
        M1 = fmaxf(M1, fmaf(fx, mb.x, fmaf(fy, mb.y, fmaf(fz, mb.z, mb.w))));
        M2 = fmaxf(M2, fmaf(fx, mc.x, fmaf(fy, mc.y, fmaf(fz, mc.z, mc.w))));
        M3 = fmaxf(M3, fmaf(fx, md.x, fmaf(fy, md.y, fmaf(fz, md.z, md.w))));
    }
    const float M = fmaxf(fmaxf(M0, M1), fmaxf(M2, M3));

    float Z0 = 0.f, Z1 = 0.f;
    char* tbb = (char*)(ws + SIMS_OFF);
#pragma unroll 2
    for (int s8 = 0; s8 < NPL; s8++) {
        h8 v;
#pragma unroll
        for (int j = 0; j < 8; j++) {
            float4 m = sm[s8 * 8 + j];
            float e = __expf(fmaf(fx, m.x, fmaf(fy, m.y, fmaf(fz, m.z, m.w))) - M);
            if (j & 1) Z1 += e; else Z0 += e;
            v[j] = (_Float16)e;
        }
        *(h8*)(tbb + ((long)(t * NPL + s8) * HW + p) * 16) = v;
    }
    ws[IZ_OFF + t * HW + p] = 1.f / (Z0 + Z1);
}

// ================= fused attn + norm + linear =================
// 16x16 tile, 1 px/thread, 49 NAMED scalar accumulators (no arrays -> no spill).
// Chunk = 4 E-planes staged plane-major: LDS slot g = jd*484 + hp (16B granules).
// MAC granule = jd*484 + q, row stride 22 (odd*2), tx stride 1 -> uniform banks.
// Double-buffered: STAGE(c+1) overlaps MAC(c), one barrier per chunk.

__device__ __forceinline__ float dot8(h8 a, h8 b, float c) {
    c = __builtin_amdgcn_fdot2(__builtin_shufflevector(a, a, 0, 1), __builtin_shufflevector(b, b, 0, 1), c, false);
    c = __builtin_amdgcn_fdot2(__builtin_shufflevector(a, a, 2, 3), __builtin_shufflevector(b, b, 2, 3), c, false);
    c = __builtin_amdgcn_fdot2(__builtin_shufflevector(a, a, 4, 5), __builtin_shufflevector(b, b, 4, 5), c, false);
    c = __builtin_amdgcn_fdot2(__builtin_shufflevector(a, a, 6, 7), __builtin_shufflevector(b, b, 6, 7), c, false);
    return c;
}

#define REP49(M) M(0)M(1)M(2)M(3)M(4)M(5)M(6)M(7)M(8)M(9)M(10)M(11)M(12)M(13) \
    M(14)M(15)M(16)M(17)M(18)M(19)M(20)M(21)M(22)M(23)M(24)M(25)M(26)M(27) \
    M(28)M(29)M(30)M(31)M(32)M(33)M(34)M(35)M(36)M(37)M(38)M(39)M(40)M(41) \
    M(42)M(43)M(44)M(45)M(46)M(47)M(48)

#define QOFF(k) (((k) / 7 - PD) * HSZ + ((k) % 7 - PD))

__launch_bounds__(256, 2)
__global__ void k_main(const float* __restrict__ x, const float* __restrict__ Wlin,
                       const float* __restrict__ blin, const float* __restrict__ ws,
                       float* __restrict__ out) {
    __shared__ __align__(16) _Float16 ssim[2 * NSLOT * 8];   // 61952 B
    __shared__ float4 sfh[NHP];                              // features + iZ
    __shared__ float  sW[441];

    const int tid = threadIdx.x;
    const int tx = tid & 15, ty = tid >> 4, lane = tid & 63;
    const int t = blockIdx.z;
    const int gx0 = blockIdx.x * 16 - PD, gy0 = blockIdx.y * 16 - PD;
    const char* tb = (const char*)(ws + SIMS_OFF);

    // staging descriptors: slot g = j*256+tid -> plane jd = g/484, halo px hp = g%484
    int off[8], step[8];
    const int zp_off = ZPB + lane * 16;
#pragma unroll
    for (int j = 0; j < 8; j++) {
        int g = j * 256 + tid;
        int jd = g / NHP;
        int hp = g - jd * NHP;
        int hy = hp / HSZ, hx = hp - hy * HSZ;
        int gy = gy0 + hy, gx = gx0 + hx;
        bool ok = (g < NSLOT) & (gy >= 0) & (gy < HH) & (gx >= 0) & (gx < WW);
        off[j] = ok ? ((t * NPL + jd) * HW + gy * WW + gx) * 16 : zp_off;
        step[j] = ok ? 4 * HW * 16 : 0;
    }

    // STAGE chunk cc into LDS buffer at dbase (cc==9: planes 38/39 -> zero pad)
#define STAGE(cc, dbase) { _Pragma("unroll") \
    for (int j = 0; j < 8; j++) { \
        int g = j * 256 + tid; \
        if (g < NSLOT) { \
            int o = (((cc) == 9) && (g >= 2 * NHP)) ? zp_off : off[j]; \
            __builtin_amdgcn_global_load_lds((const void*)(tb + o), \
                (void*)((dbase) + ((j * 256 + (tid & 192)) << 4)), 16, 0, 0); \
            off[j] += step[j]; \
        } } }

    char* bufA = (char*)ssim;
    char* bufB = (char*)ssim + NSLOT * 16;
    STAGE(0, bufA)

    for (int i = tid; i < 441; i += 256) sW[i] = Wlin[i];
    const float* izp = ws + IZ_OFF + t * HW;
    for (int hp = tid; hp < NHP; hp += 256) {
        int hy = hp / HSZ, hx = hp - hy * HSZ;
        int gy = gy0 + hy, gx = gx0 + hx;
        bool inb = (gy >= 0 && gy < HH && gx >= 0 && gx < WW);
        float4 f = make_float4(0.f, 0.f, 0.f, 0.f);
        if (inb) {
            int p = gy * WW + gx;
            f.x = x[(t * 3 + 0) * HW + p];
            f.y = x[(t * 3 + 1) * HW + p];
            f.z = x[(t * 3 + 2) * HW + p];
            f.w = izp[p];
        }
        sfh[hp] = f;
    }

#define ZK(k) float acc##k = 0.f;
    REP49(ZK)
#undef ZK
    const int own = (ty + PD) * HSZ + (tx + PD);
    const char* pbA = bufA + (own - 69) * 16;   // q-granule k,jd at literal offset
    const char* pbB = bufB + (own - 69) * 16;

    __syncthreads();   // STAGE(0) drained (barrier waits vmcnt), sfh/sW visible

#pragma unroll 1
    for (int c = 0; c < 10; ++c) {
        char* db = (c & 1) ? bufA : bufB;
        if (c < 9) { STAGE(c + 1, db) }
        const char* pb = (c & 1) ? pbB : pbA;
        h8 o0 = *(const h8*)(pb + (69 + 0 * NHP) * 16);
        h8 o1 = *(const h8*)(pb + (69 + 1 * NHP) * 16);
        h8 o2 = *(const h8*)(pb + (69 + 2 * NHP) * 16);
        h8 o3 = *(const h8*)(pb + (69 + 3 * NHP) * 16);
#define MACK(k) { \
        h8 q0 = *(const h8*)(pb + ((QOFF(k) + 69 + 0 * NHP) * 16)); \
        h8 q1 = *(const h8*)(pb + ((QOFF(k) + 69 + 1 * NHP) * 16)); \
        h8 q2 = *(const h8*)(pb + ((QOFF(k) + 69 + 2 * NHP) * 16)); \
        h8 q3 = *(const h8*)(pb + ((QOFF(k) + 69 + 3 * NHP) * 16)); \
        float aA = acc##k, aB = 0.f; \
        aA = dot8(o0, q0, aA); aB = dot8(o1, q1, aB); \
        aA = dot8(o2, q2, aA); aB = dot8(o3, q3, aB); \
        acc##k = aA + aB; }
        REP49(MACK)
#undef MACK
        __syncthreads();   // MAC(c) reads done; STAGE(c+1) DMA drained
    }

    // ---- normalize (eps+max semantics) + linear epilogue ----
    // true rw_k = acc_k * iZ_p * iZ_q; divide by (eps + max_k rw_k)
#define IZK(k) acc##k *= sfh[own + QOFF(k)].w;
    REP49(IZK)
#undef IZK
    float mx = 0.f;
#define MXK(k) mx = fmaxf(mx, acc##k);
    REP49(MXK)
#undef MXK
    const float iZ0 = sfh[own].w;
    const float inv = 1.f / (1e-5f / iZ0 + mx);

    float o0 = blin[0], o1 = blin[1], o2 = blin[2];
#define EPIK(k) { \
        float rwk = acc##k * inv; \
        float4 f = sfh[own + QOFF(k)]; \
        o0 += rwk * (sW[k] * f.x + sW[49 + (k)] * f.y + sW[98 + (k)] * f.z); \
        o1 += rwk * (sW[147 + (k)] * f.x + sW[196 + (k)] * f.y + sW[245 + (k)] * f.z); \
        o2 += rwk * (sW[294 + (k)] * f.x + sW[343 + (k)] * f.y + sW[392 + (k)] * f.z); }
    REP49(EPIK)
#undef EPIK

    int p = (gy0 + PD + ty) * WW + gx0 + PD + tx;
    out[(t * 3 + 0) * HW + p] = o0;
    out[(t * 3 + 1) * HW + p] = o1;
    out[(t * 3 + 2) * HW + p] = o2;
}

extern "C" void kernel_launch(void* const* d_in, const int* in_sizes, int n_in,
                              void* d_out, int out_size, void* d_ws, size_t ws_size,
                              hipStream_t stream) {
    (void)in_sizes; (void)n_in; (void)out_size; (void)ws_size;
    const float* x    = (const float*)d_in[0];
    const int*   spix = (const int*)d_in[1];
    const float* Wlin = (const float*)d_in[2];
    const float* blin = (const float*)d_in[3];
    float* out = (float*)d_out;
    float* ws  = (float*)d_ws;

    hipLaunchKernelGGL(k_zero,  dim3(20), dim3(256), 0, stream, ws);
    hipLaunchKernelGGL(k_accum, dim3((TT * HW + 255) / 256), dim3(256), 0, stream, x, spix, ws);
    hipLaunchKernelGGL(k_means, dim3((TT * SP + 255) / 256), dim3(256), 0, stream, ws);
    hipLaunchKernelGGL(k_sims,  dim3(HW / 256, TT), dim3(256), 0, stream, x, ws);
    hipLaunchKernelGGL(k_main,  dim3(WW / 16, HH / 16, TT), dim3(256), 0, stream,
                       x, Wlin, blin, ws, out);
}

// Round 7
// 186.273 us; speedup vs baseline: 9.0149x; 1.0498x over previous
//
#include <hip/hip_runtime.h>
#include <math.h>

#define TT 4
#define HH 192
#define WW 192
#define SS 300
#define SP 320              // padded superpixel count (pad masked -inf)
#define HW (HH*WW)
#define PD 3
#define HSZ 22
#define NHP 484             // 22*22 halo pixels
#define NG 1936             // 16B granules per chunk buffer (4 planes x 484)
#define LOG2E 1.44269504088896340736f

typedef _Float16 h8 __attribute__((ext_vector_type(8)));
typedef float f4 __attribute__((ext_vector_type(4)));

// ---------- ws layout (floats) ----------
// [0, 3600)    sums [T][S][3]
// [3600, 4800) cnts [T][S]
// [4800, 9920) means float4 [T][SP]: ((20/ln2)m, w = (-10/ln2)|m|^2 | -inf absent)

__global__ void k_zero(float* ws) {
    int i = blockIdx.x * 256 + threadIdx.x;
    if (i < TT * SS * 4) ws[i] = 0.f;
}

__global__ void k_accum(const float* __restrict__ x, const int* __restrict__ spix,
                        float* __restrict__ ws) {
    int i = blockIdx.x * 256 + threadIdx.x;
    if (i >= TT * HW) return;
    int t = i / HW, p = i - t * HW;
    int s = spix[i];
    float* sums = ws;
    float* cnts = ws + TT * SS * 3;
    int b = (t * SS + s) * 3;
    atomicAdd(&sums[b + 0], x[(t * 3 + 0) * HW + p]);
    atomicAdd(&sums[b + 1], x[(t * 3 + 1) * HW + p]);
    atomicAdd(&sums[b + 2], x[(t * 3 + 2) * HW + p]);
    atomicAdd(&cnts[t * SS + s], 1.f);
}

__global__ void k_means(float* __restrict__ ws) {
    int i = blockIdx.x * 256 + threadIdx.x;
    if (i >= TT * SP) return;
    int t = i / SP, s = i - t * SP;
    const float* sums = ws;
    const float* cnts = ws + TT * SS * 3;
    float4* m4 = (float4*)(ws + 4800);
    float4 m;
    if (s < SS) {
        float c = cnts[t * SS + s];
        float inv = 1.f / fmaxf(c, 1.f);
        float mx = sums[(t * SS + s) * 3 + 0] * inv;
        float my = sums[(t * SS + s) * 3 + 1] * inv;
        float mz = sums[(t * SS + s) * 3 + 2] * inv;
        m.x = 20.f * LOG2E * mx; m.y = 20.f * LOG2E * my; m.z = 20.f * LOG2E * mz;
        m.w = (c > 0.f) ? (-10.f * LOG2E * (mx * mx + my * my + mz * mz)) : -INFINITY;
    } else {
        m.x = 0.f; m.y = 0.f; m.z = 0.f; m.w = -INFINITY;
    }
    m4[t * SP + s] = m;
}

#define REP49(M) M(0)M(1)M(2)M(3)M(4)M(5)M(6)M(7)M(8)M(9)M(10)M(11)M(12)M(13) \
    M(14)M(15)M(16)M(17)M(18)M(19)M(20)M(21)M(22)M(23)M(24)M(25)M(26)M(27) \
    M(28)M(29)M(30)M(31)M(32)M(33)M(34)M(35)M(36)M(37)M(38)M(39)M(40)M(41) \
    M(42)M(43)M(44)M(45)M(46)M(47)M(48)

#define QOFF(k) (((k) / 7 - PD) * HSZ + ((k) % 7 - PD))

// ================= fused: sims (in-LDS) + MFMA attn + norm + linear =================
// 16x16 tile, 512 threads (8 waves). Halo 22x22 = 484 px, 1 thread per halo px for
// phases A/B. E chunk = 32 s (4 planes) in LDS, plane-major granules (jd*484+px),
// double-buffered. MFMA: wave w owns p-rows {2w, 2w+1}; per chunk per row:
// A = E[row px 0..15], B1/B2 = E[q-row window cols]; D[i,j] = sum_s E_p E_q (band).
// attn gathered to an LDS overlay (stride 51) after the chunk loop; epilogue as before.

__launch_bounds__(512, 2)
__global__ void k_main(const float* __restrict__ x, const float* __restrict__ Wlin,
                       const float* __restrict__ blin, const float* __restrict__ ws,
                       float* __restrict__ out) {
    __shared__ __align__(16) char ebuf[2][NG * 16];   // 61952 B (attn overlay reuses this)
    __shared__ float4 sfh[NHP];                       // xyz = feature, w = iZ (0 if OOB)
    __shared__ float  sW[441];

    const int tid = threadIdx.x;
    const int wid = tid >> 6, lane = tid & 63;
    const int pxc = lane & 15, kg = lane >> 4;        // MFMA fragment coords
    const int t = blockIdx.z;
    const int gx0 = blockIdx.x * 16 - PD, gy0 = blockIdx.y * 16 - PD;
    const float4* m4 = (const float4*)(ws + 4800) + t * SP;

    for (int i = tid; i < 441; i += 512) sW[i] = Wlin[i];

    // ---- per-halo-pixel state + phase A (max logit M) ----
    float fx = 0.f, fy = 0.f, fz = 0.f, M = INFINITY, z = 0.f;
    bool inb = false;
    if (tid < NHP) {
        int hy = tid / HSZ, hx = tid - hy * HSZ;
        int gy = gy0 + hy, gx = gx0 + hx;
        inb = (gy >= 0 && gy < HH && gx >= 0 && gx < WW);
        if (inb) {
            int p = gy * WW + gx;
            fx = x[(t * 3 + 0) * HW + p];
            fy = x[(t * 3 + 1) * HW + p];
            fz = x[(t * 3 + 2) * HW + p];
            float m0 = -INFINITY, m1 = -INFINITY;
#pragma unroll 2
            for (int s = 0; s < SP; s += 2) {
                float4 a = m4[s], b = m4[s + 1];
                m0 = fmaxf(m0, fmaf(fx, a.x, fmaf(fy, a.y, fmaf(fz, a.z, a.w))));
                m1 = fmaxf(m1, fmaf(fx, b.x, fmaf(fy, b.y, fmaf(fz, b.z, b.w))));
            }
            M = fmaxf(m0, m1);      // finite (softmax shift); OOB px keep M=+inf -> E=0
        }
        sfh[tid] = make_float4(fx, fy, fz, 0.f);
    }

    // phase B: E values for chunk cc -> buffer bb; accumulate Z
#define PHASEB(cc, bb) if (tid < NHP) { \
        float zl = 0.f; \
        char* dst = ebuf[bb]; \
        _Pragma("unroll") \
        for (int jd = 0; jd < 4; jd++) { \
            h8 v; \
            _Pragma("unroll") \
            for (int e = 0; e < 8; e++) { \
                float4 m = m4[(cc) * 32 + jd * 8 + e]; \
                float E = exp2f(fmaf(fx, m.x, fmaf(fy, m.y, fmaf(fz, m.z, m.w))) - M); \
                zl += E; v[e] = (_Float16)E; \
            } \
            *(h8*)(dst + (jd * NHP + tid) * 16) = v; \
        } \
        z += zl; }

    // ---- MFMA setup: wave owns rows r0, r0+1 of the 16x16 tile ----
    const int r0 = 2 * wid;
    const int gA0 = kg * NHP + (r0 + PD) * HSZ + PD + pxc;          // A row r0
    const int gA1 = gA0 + HSZ;                                      // A row r0+1
    const int bcol2 = (16 + pxc > 21) ? 21 : 16 + pxc;              // clamped tile2 col
    const int gB1 = kg * NHP + r0 * HSZ + pxc;                      // + d*HSZ
    const int gB2 = kg * NHP + r0 * HSZ + bcol2;                    // + d*HSZ

    f4 zero4 = {0.f, 0.f, 0.f, 0.f};
    f4 aP[7], aQ[7], aR[7], aS[7];   // (A0,B1) (A0,B2) (A1,B1') (A1,B2')
#pragma unroll
    for (int d = 0; d < 7; d++) { aP[d] = zero4; aQ[d] = zero4; aR[d] = zero4; aS[d] = zero4; }

    PHASEB(0, 0)

#pragma unroll 1
    for (int c = 0; c < 10; c++) {
        __syncthreads();               // phaseB(c) visible; MFMA(c-1) reads done
        if (c < 9) { PHASEB(c + 1, (c + 1) & 1) }
        const char* pb = ebuf[c & 1];
        h8 A0 = *(const h8*)(pb + gA0 * 16);
        h8 A1 = *(const h8*)(pb + gA1 * 16);
#pragma unroll
        for (int d = 0; d < 7; d++) {
            h8 B1a = *(const h8*)(pb + (gB1 + d * HSZ) * 16);
            h8 B2a = *(const h8*)(pb + (gB2 + d * HSZ) * 16);
            h8 B1b = *(const h8*)(pb + (gB1 + (d + 1) * HSZ) * 16);
            h8 B2b = *(const h8*)(pb + (gB2 + (d + 1) * HSZ) * 16);
            aP[d] = __builtin_amdgcn_mfma_f32_16x16x32_f16(A0, B1a, aP[d], 0, 0, 0);
            aQ[d] = __builtin_amdgcn_mfma_f32_16x16x32_f16(A0, B2a, aQ[d], 0, 0, 0);
            aR[d] = __builtin_amdgcn_mfma_f32_16x16x32_f16(A1, B1b, aR[d], 0, 0, 0);
            aS[d] = __builtin_amdgcn_mfma_f32_16x16x32_f16(A1, B2b, aS[d], 0, 0, 0);
        }
    }
    __syncthreads();                   // last MFMA reads done; ebuf reusable

    if (tid < NHP) ((float*)&sfh[tid])[3] = inb ? (1.f / z) : 0.f;   // iZ (0 for OOB)

    // ---- band write-out: D[i = 4*kg+reg, j = pxc] -> attn[px][k] (each slot once) ----
    float* attn = (float*)ebuf;        // [256 px][stride 51] f32, 52.2 KB < 62 KB
#pragma unroll
    for (int d = 0; d < 7; d++) {
#pragma unroll
        for (int reg = 0; reg < 4; reg++) {
            int i = 4 * kg + reg;
            int u1 = pxc - i;          // tile1: dx+3 = j-i
            int u2 = u1 + 16;          // tile2: dx+3 = 16+j-i
            if ((unsigned)u1 <= 6u) {
                attn[(r0 * 16 + i) * 51 + d * 7 + u1] = aP[d][reg];
                attn[((r0 + 1) * 16 + i) * 51 + d * 7 + u1] = aR[d][reg];
            }
            if ((unsigned)u2 <= 6u) {
                attn[(r0 * 16 + i) * 51 + d * 7 + u2] = aQ[d][reg];
                attn[((r0 + 1) * 16 + i) * 51 + d * 7 + u2] = aS[d][reg];
            }
        }
    }
    __syncthreads();

    // ---- normalize (eps+max semantics) + linear epilogue (1 thread / pixel) ----
    if (tid < 256) {
        const int r = tid >> 4, cq = tid & 15;
        const int own = (r + PD) * HSZ + (cq + PD);
        const float* ap = attn + tid * 51;
        float mx = 0.f;
#define PK1(k) mx = fmaxf(mx, ap[k] * sfh[own + QOFF(k)].w);
        REP49(PK1)
#undef PK1
        const float iZp = sfh[own].w;
        const float inv = 1.f / (1e-5f / iZp + mx);

        float o0 = blin[0], o1 = blin[1], o2 = blin[2];
#define PK2(k) { float4 f = sfh[own + QOFF(k)]; \
        float rwk = ap[k] * f.w * inv; \
        o0 += rwk * (sW[k] * f.x + sW[49 + (k)] * f.y + sW[98 + (k)] * f.z); \
        o1 += rwk * (sW[147 + (k)] * f.x + sW[196 + (k)] * f.y + sW[245 + (k)] * f.z); \
        o2 += rwk * (sW[294 + (k)] * f.x + sW[343 + (k)] * f.y + sW[392 + (k)] * f.z); }
        REP49(PK2)
#undef PK2

        int p = (gy0 + PD + r) * WW + gx0 + PD + cq;
        out[(t * 3 + 0) * HW + p] = o0;
        out[(t * 3 + 1) * HW + p] = o1;
        out[(t * 3 + 2) * HW + p] = o2;
    }
}

extern "C" void kernel_launch(void* const* d_in, const int* in_sizes, int n_in,
                              void* d_out, int out_size, void* d_ws, size_t ws_size,
                              hipStream_t stream) {
    (void)in_sizes; (void)n_in; (void)out_size; (void)ws_size;
    const float* x    = (const float*)d_in[0];
    const int*   spix = (const int*)d_in[1];
    const float* Wlin = (const float*)d_in[2];
    const float* blin = (const float*)d_in[3];
    float* out = (float*)d_out;
    float* ws  = (float*)d_ws;

    hipLaunchKernelGGL(k_zero,  dim3(19), dim3(256), 0, stream, ws);
    hipLaunchKernelGGL(k_accum, dim3((TT * HW + 255) / 256), dim3(256), 0, stream, x, spix, ws);
    hipLaunchKernelGGL(k_means, dim3((TT * SP + 255) / 256), dim3(256), 0, stream, ws);
    hipLaunchKernelGGL(k_main,  dim3(WW / 16, HH / 16, TT), dim3(512), 0, stream,
                       x, Wlin, blin, ws, out);
}

// Round 9
// 132.406 us; speedup vs baseline: 12.6825x; 1.4068x over previous
//
#include <hip/hip_runtime.h>
#include <math.h>

#define TT 4
#define HH 192
#define WW 192
#define SS 300
#define SP 320              // padded superpixel count (pad masked -inf)
#define HW (HH*WW)
#define PD 3
#define HSZ 22
#define NHP 484             // 22*22 halo pixels
#define NG 1936             // 16B granules per chunk buffer (4 planes x 484)
#define LOG2E 1.44269504088896340736f
#define MOFF 16384          // float index of M table [T][HW]
#define ZOFF (MOFF + TT*HW) // float index of iZ table [T][HW]

typedef _Float16 h8 __attribute__((ext_vector_type(8)));
typedef float f4 __attribute__((ext_vector_type(4)));

// ---------- ws layout (floats) ----------
// [0, 3600)    sums [T][S][3]
// [3600, 4800) cnts [T][S]
// [4800, 9920) means float4 [T][SP]: ((20/ln2)m, w = (-10/ln2)|m|^2 | -inf absent)
// [MOFF ...)   per-pixel max logit M (f32), then iZ = 1/Z (f32)

__global__ void k_zero(float* ws) {
    int i = blockIdx.x * 256 + threadIdx.x;
    if (i < TT * SS * 4) ws[i] = 0.f;
}

// LDS-staged superpixel accumulation: 16 segments x 2304 px per frame
__launch_bounds__(256)
__global__ void k_accum(const float* __restrict__ x, const int* __restrict__ spix,
                        float* __restrict__ ws) {
    __shared__ float ls[SS * 4];
    const int tid = threadIdx.x;
    const int t = blockIdx.y, seg = blockIdx.x;
    for (int i = tid; i < SS * 4; i += 256) ls[i] = 0.f;
    __syncthreads();
#pragma unroll
    for (int it = 0; it < 9; it++) {
        int px = seg * 2304 + it * 256 + tid;
        int s = spix[t * HW + px];
        atomicAdd(&ls[s * 4 + 0], x[(t * 3 + 0) * HW + px]);
        atomicAdd(&ls[s * 4 + 1], x[(t * 3 + 1) * HW + px]);
        atomicAdd(&ls[s * 4 + 2], x[(t * 3 + 2) * HW + px]);
        atomicAdd(&ls[s * 4 + 3], 1.f);
    }
    __syncthreads();
    for (int i = tid; i < SS * 4; i += 256) {
        float v = ls[i];
        if (v != 0.f) {
            int s = i >> 2, c = i & 3;
            if (c < 3) atomicAdd(&ws[(t * SS + s) * 3 + c], v);
            else       atomicAdd(&ws[3600 + t * SS + s], v);
        }
    }
}

__global__ void k_means(float* __restrict__ ws) {
    int i = blockIdx.x * 256 + threadIdx.x;
    if (i >= TT * SP) return;
    int t = i / SP, s = i - t * SP;
    const float* sums = ws;
    const float* cnts = ws + TT * SS * 3;
    float4* m4 = (float4*)(ws + 4800);
    float4 m;
    if (s < SS) {
        float c = cnts[t * SS + s];
        float inv = 1.f / fmaxf(c, 1.f);
        float mx = sums[(t * SS + s) * 3 + 0] * inv;
        float my = sums[(t * SS + s) * 3 + 1] * inv;
        float mz = sums[(t * SS + s) * 3 + 2] * inv;
        m.x = 20.f * LOG2E * mx; m.y = 20.f * LOG2E * my; m.z = 20.f * LOG2E * mz;
        m.w = (c > 0.f) ? (-10.f * LOG2E * (mx * mx + my * my + mz * mz)) : -INFINITY;
    } else {
        m.x = 0.f; m.y = 0.f; m.z = 0.f; m.w = -INFINITY;
    }
    m4[t * SP + s] = m;
}

// ---- per-pixel max logit M and iZ = 1/sum(exp2(logit - M)), full occupancy ----
__launch_bounds__(256)
__global__ void k_prep(const float* __restrict__ x, float* __restrict__ ws) {
    __shared__ float4 sm[SP];
    const int tid = threadIdx.x;
    const int t = blockIdx.y;
    const int p = blockIdx.x * 256 + tid;
    const float4* m4 = (const float4*)(ws + 4800) + t * SP;
    for (int i = tid; i < SP; i += 256) sm[i] = m4[i];
    __syncthreads();
    const float fx = x[(t * 3 + 0) * HW + p];
    const float fy = x[(t * 3 + 1) * HW + p];
    const float fz = x[(t * 3 + 2) * HW + p];

    float M0 = -INFINITY, M1 = -INFINITY;
#pragma unroll 4
    for (int s = 0; s < SP; s += 2) {
        float4 a = sm[s], b = sm[s + 1];
        M0 = fmaxf(M0, fmaf(fx, a.x, fmaf(fy, a.y, fmaf(fz, a.z, a.w))));
        M1 = fmaxf(M1, fmaf(fx, b.x, fmaf(fy, b.y, fmaf(fz, b.z, b.w))));
    }
    const float M = fmaxf(M0, M1);
    float Z0 = 0.f, Z1 = 0.f;
#pragma unroll 4
    for (int s = 0; s < SP; s += 2) {
        float4 a = sm[s], b = sm[s + 1];
        Z0 += exp2f(fmaf(fx, a.x, fmaf(fy, a.y, fmaf(fz, a.z, a.w))) - M);
        Z1 += exp2f(fmaf(fx, b.x, fmaf(fy, b.y, fmaf(fz, b.z, b.w))) - M);
    }
    ws[MOFF + t * HW + p] = M;
    ws[ZOFF + t * HW + p] = 1.f / (Z0 + Z1);
}

#define REP49(M) M(0)M(1)M(2)M(3)M(4)M(5)M(6)M(7)M(8)M(9)M(10)M(11)M(12)M(13) \
    M(14)M(15)M(16)M(17)M(18)M(19)M(20)M(21)M(22)M(23)M(24)M(25)M(26)M(27) \
    M(28)M(29)M(30)M(31)M(32)M(33)M(34)M(35)M(36)M(37)M(38)M(39)M(40)M(41) \
    M(42)M(43)M(44)M(45)M(46)M(47)M(48)

#define QOFF(k) (((k) / 7 - PD) * HSZ + ((k) % 7 - PD))

// ================= fused: E (in-LDS) + MFMA attn + norm + linear =================
// 16x16 tile, 512 threads. E chunk = 32 s (4 planes of 8) in LDS, plane-major
// granules (jd*484+px), double-buffered. MFMA: wave w owns p-rows {2w,2w+1};
// B-fragment reuse: B[d] feeds row r0 (offset d) AND row r0+1 (offset d-1).
// attn gathered via LDS overlay (stride 51); epilogue 1 thread/px.

__launch_bounds__(512, 2)
__global__ void k_main(const float* __restrict__ x, const float* __restrict__ Wlin,
                       const float* __restrict__ blin, const float* __restrict__ ws,
                       float* __restrict__ out) {
    __shared__ __align__(16) char ebuf[2][NG * 16];   // 61952 B (attn overlay reuses this)
    __shared__ float4 sfh[NHP];                       // xyz = feature, w = iZ (0 if OOB)
    __shared__ float  sW[441];

    const int tid = threadIdx.x;
    const int wid = tid >> 6, lane = tid & 63;
    const int pxc = lane & 15, kg = lane >> 4;        // MFMA fragment coords
    const int t = blockIdx.z;
    const int gx0 = blockIdx.x * 16 - PD, gy0 = blockIdx.y * 16 - PD;
    const float4* m4 = (const float4*)(ws + 4800) + t * SP;

    for (int i = tid; i < 441; i += 512) sW[i] = Wlin[i];

    // ---- per-halo-pixel state (loads only; M/iZ precomputed) ----
    float fx = 0.f, fy = 0.f, fz = 0.f, M = INFINITY;
    if (tid < NHP) {
        int hy = tid / HSZ, hx = tid - hy * HSZ;
        int gy = gy0 + hy, gx = gx0 + hx;
        float iZ = 0.f;
        if (gy >= 0 && gy < HH && gx >= 0 && gx < WW) {
            int p = gy * WW + gx;
            fx = x[(t * 3 + 0) * HW + p];
            fy = x[(t * 3 + 1) * HW + p];
            fz = x[(t * 3 + 2) * HW + p];
            M  = ws[MOFF + t * HW + p];
            iZ = ws[ZOFF + t * HW + p];
        }
        sfh[tid] = make_float4(fx, fy, fz, iZ);
    }

    // phase B: E values for chunk cc -> buffer bb (OOB px: M=+inf -> E=0)
#define PHASEB(cc, bb) if (tid < NHP) { \
        char* dst = ebuf[bb]; \
        _Pragma("unroll") \
        for (int jd = 0; jd < 4; jd++) { \
            h8 v; \
            _Pragma("unroll") \
            for (int e = 0; e < 4; e++) { \
                float4 ma = m4[(cc) * 32 + jd * 8 + 2 * e]; \
                float4 mb = m4[(cc) * 32 + jd * 8 + 2 * e + 1]; \
                float E0 = exp2f(fmaf(fx, ma.x, fmaf(fy, ma.y, fmaf(fz, ma.z, ma.w))) - M); \
                float E1 = exp2f(fmaf(fx, mb.x, fmaf(fy, mb.y, fmaf(fz, mb.z, mb.w))) - M); \
                auto pr = __builtin_amdgcn_cvt_pkrtz(E0, E1); \
                v[2 * e] = (_Float16)pr.x; v[2 * e + 1] = (_Float16)pr.y; \
            } \
            *(h8*)(dst + (jd * NHP + tid) * 16) = v; \
        } }

    // ---- MFMA setup: wave owns rows r0, r0+1 of the 16x16 tile ----
    const int r0 = 2 * wid;
    const int gA0 = kg * NHP + (r0 + PD) * HSZ + PD + pxc;          // A row r0
    const int gA1 = gA0 + HSZ;                                      // A row r0+1
    const int bcol2 = (16 + pxc > 21) ? 21 : 16 + pxc;              // clamped tile2 col
    const int gB1 = kg * NHP + r0 * HSZ + pxc;                      // + d*HSZ
    const int gB2 = kg * NHP + r0 * HSZ + bcol2;                    // + d*HSZ

    f4 zero4 = {0.f, 0.f, 0.f, 0.f};
    f4 aP[7], aQ[7], aR[7], aS[7];   // (A0,B1[d]) (A0,B2[d]) (A1,B1[d+1]) (A1,B2[d+1])
#pragma unroll
    for (int d = 0; d < 7; d++) { aP[d] = zero4; aQ[d] = zero4; aR[d] = zero4; aS[d] = zero4; }

    PHASEB(0, 0)

#pragma unroll 1
    for (int c = 0; c < 10; c++) {
        __syncthreads();               // phaseB(c) visible; MFMA(c-1) reads done
        if (c < 9) { PHASEB(c + 1, (c + 1) & 1) }
        const char* pb = ebuf[c & 1];
        h8 A0 = *(const h8*)(pb + gA0 * 16);
        h8 A1 = *(const h8*)(pb + gA1 * 16);
        // d = 0: B[0] feeds row r0 only
        h8 b1 = *(const h8*)(pb + gB1 * 16);
        h8 b2 = *(const h8*)(pb + gB2 * 16);
        aP[0] = __builtin_amdgcn_mfma_f32_16x16x32_f16(A0, b1, aP[0], 0, 0, 0);
        aQ[0] = __builtin_amdgcn_mfma_f32_16x16x32_f16(A0, b2, aQ[0], 0, 0, 0);
#pragma unroll
        for (int d = 1; d < 7; d++) {  // B[d] feeds row r0 (as d) and row r0+1 (as d-1)
            h8 n1 = *(const h8*)(pb + (gB1 + d * HSZ) * 16);
            h8 n2 = *(const h8*)(pb + (gB2 + d * HSZ) * 16);
            aP[d]     = __builtin_amdgcn_mfma_f32_16x16x32_f16(A0, n1, aP[d], 0, 0, 0);
            aR[d - 1] = __builtin_amdgcn_mfma_f32_16x16x32_f16(A1, n1, aR[d - 1], 0, 0, 0);
            aQ[d]     = __builtin_amdgcn_mfma_f32_16x16x32_f16(A0, n2, aQ[d], 0, 0, 0);
            aS[d - 1] = __builtin_amdgcn_mfma_f32_16x16x32_f16(A1, n2, aS[d - 1], 0, 0, 0);
        }
        // d = 7: B[7] feeds row r0+1 only
        h8 l1 = *(const h8*)(pb + (gB1 + 7 * HSZ) * 16);
        h8 l2 = *(const h8*)(pb + (gB2 + 7 * HSZ) * 16);
        aR[6] = __builtin_amdgcn_mfma_f32_16x16x32_f16(A1, l1, aR[6], 0, 0, 0);
        aS[6] = __builtin_amdgcn_mfma_f32_16x16x32_f16(A1, l2, aS[6], 0, 0, 0);
    }
    __syncthreads();                   // last MFMA reads done; ebuf reusable

    // ---- band write-out: D[i = 4*kg+reg, j = pxc] -> attn[px][k] (each slot once) ----
    float* attn = (float*)ebuf;        // [256 px][stride 51] f32, 52.2 KB < 62 KB
#pragma unroll
    for (int d = 0; d < 7; d++) {
#pragma unroll
        for (int reg = 0; reg < 4; reg++) {
            int i = 4 * kg + reg;
            int u1 = pxc - i;          // tile1: dx+3 = j-i
            int u2 = u1 + 16;          // tile2: dx+3 = 16+j-i
            if ((unsigned)u1 <= 6u) {
                attn[(r0 * 16 + i) * 51 + d * 7 + u1] = aP[d][reg];
                attn[((r0 + 1) * 16 + i) * 51 + d * 7 + u1] = aR[d][reg];
            }
            if ((unsigned)u2 <= 6u) {
                attn[(r0 * 16 + i) * 51 + d * 7 + u2] = aQ[d][reg];
                attn[((r0 + 1) * 16 + i) * 51 + d * 7 + u2] = aS[d][reg];
            }
        }
    }
    __syncthreads();

    // ---- normalize (eps+max semantics) + linear epilogue (1 thread / pixel) ----
    if (tid < 256) {
        const int r = tid >> 4, cq = tid & 15;
        const int own = (r + PD) * HSZ + (cq + PD);
        const float* ap = attn + tid * 51;
        float mx = 0.f;
#define PK1(k) mx = fmaxf(mx, ap[k] * sfh[own + QOFF(k)].w);
        REP49(PK1)
#undef PK1
        const float iZp = sfh[own].w;
        const float inv = 1.f / (1e-5f / iZp + mx);

        float o0 = blin[0], o1 = blin[1], o2 = blin[2];
#define PK2(k) { float4 f = sfh[own + QOFF(k)]; \
        float rwk = ap[k] * f.w * inv; \
        o0 += rwk * (sW[k] * f.x + sW[49 + (k)] * f.y + sW[98 + (k)] * f.z); \
        o1 += rwk * (sW[147 + (k)] * f.x + sW[196 + (k)] * f.y + sW[245 + (k)] * f.z); \
        o2 += rwk * (sW[294 + (k)] * f.x + sW[343 + (k)] * f.y + sW[392 + (k)] * f.z); }
        REP49(PK2)
#undef PK2

        int p = (gy0 + PD + r) * WW + gx0 + PD + cq;
        out[(t * 3 + 0) * HW + p] = o0;
        out[(t * 3 + 1) * HW + p] = o1;
        out[(t * 3 + 2) * HW + p] = o2;
    }
}

extern "C" void kernel_launch(void* const* d_in, const int* in_sizes, int n_in,
                              void* d_out, int out_size, void* d_ws, size_t ws_size,
                              hipStream_t stream) {
    (void)in_sizes; (void)n_in; (void)out_size; (void)ws_size;
    const float* x    = (const float*)d_in[0];
    const int*   spix = (const int*)d_in[1];
    const float* Wlin = (const float*)d_in[2];
    const float* blin = (const float*)d_in[3];
    float* out = (float*)d_out;
    float* ws  = (float*)d_ws;

    hipLaunchKernelGGL(k_zero,  dim3(19), dim3(256), 0, stream, ws);
    hipLaunchKernelGGL(k_accum, dim3(16, TT), dim3(256), 0, stream, x, spix, ws);
    hipLaunchKernelGGL(k_means, dim3((TT * SP + 255) / 256), dim3(256), 0, stream, ws);
    hipLaunchKernelGGL(k_prep,  dim3(HW / 256, TT), dim3(256), 0, stream, x, ws);
    hipLaunchKernelGGL(k_main,  dim3(WW / 16, HH / 16, TT), dim3(512), 0, stream,
                       x, Wlin, blin, ws, out);
}